// Round 1
// baseline (489.726 us; speedup 1.0000x reference)
//
#include <hip/hip_runtime.h>
#include <math.h>

#define H 256
#define V 32000
#define L 2048
#define B 64
#define NCH 16          // context l-chunks

// ws layout (float offsets)
#define WS_W      0                       // [2H] = attn_W^T @ flatten
#define WS_BIAS   512                     // [1]
#define WS_EH     513                     // [B]
#define WS_ENERGY 640                     // [B*L]
#define WS_PART   (640 + B*L)             // [NCH*B*H] context partials
#define WS_XCAT   (WS_PART + NCH*B*H)     // [B*2H] = [h_new ; context]
#define WS_M      (WS_XCAT + B*2*H)       // [B] row max
#define WS_S      (WS_M + B)              // [B] log(sum exp)

// ---------------- k1: w = attn_W^T @ fvec, bias = fvec.attn_b, e_h = h @ w[:H]
__global__ __launch_bounds__(512) void k1_prep(
    const float* __restrict__ attn_W, const float* __restrict__ attn_b,
    const float* __restrict__ flatten, const float* __restrict__ hidden,
    float* __restrict__ ws) {
  __shared__ float fv[H];
  __shared__ float w_s[2 * H];
  __shared__ float red[H];
  int tid = threadIdx.x;  // 512 threads
  if (tid < H) fv[tid] = flatten[tid];
  __syncthreads();
  // w[tid] = sum_h attn_W[h, tid] * fv[h]  (coalesced row reads of attn_W)
  float acc = 0.f;
  for (int hh = 0; hh < H; ++hh) acc += attn_W[hh * 2 * H + tid] * fv[hh];
  w_s[tid] = acc;
  ws[WS_W + tid] = acc;
  if (tid < H) red[tid] = fv[tid] * attn_b[tid];
  __syncthreads();
  for (int s = H / 2; s > 0; s >>= 1) {
    if (tid < s) red[tid] += red[tid + s];
    __syncthreads();
  }
  if (tid == 0) ws[WS_BIAS] = red[0];
  // e_h[b] = hidden[b,:] . w[:H]
  if (tid < B) {
    float a = 0.f;
    for (int h = 0; h < H; ++h) a += hidden[tid * H + h] * w_s[h];
    ws[WS_EH + tid] = a;
  }
}

// ---------------- k2: energies[b,l] = enc[l,b,:].w[H:] + e_h[b] + bias
// one wave per (l,b) pair; lane does a float4 slice of the H=256 dot.
__global__ __launch_bounds__(256) void k2_energy(
    const float* __restrict__ enc, float* __restrict__ ws) {
  int tid = threadIdx.x;
  int lane = tid & 63;
  size_t pair = (size_t)blockIdx.x * 4 + (tid >> 6);  // < L*B = 131072
  const float4* e4 = (const float4*)enc;
  float4 e = e4[pair * (H / 4) + lane];
  float4 w2 = ((const float4*)(ws + WS_W + H))[lane];
  float v = e.x * w2.x + e.y * w2.y + e.z * w2.z + e.w * w2.w;
  for (int off = 32; off > 0; off >>= 1) v += __shfl_xor(v, off, 64);
  if (lane == 0) {
    int b = (int)(pair & (B - 1));
    int l = (int)(pair >> 6);
    ws[WS_ENERGY + b * L + l] = v + ws[WS_EH + b] + ws[WS_BIAS];
  }
}

// ---------------- k3: softmax over L per batch row -> attn_weights in d_out
__global__ __launch_bounds__(256) void k3_softmax(
    const float* __restrict__ ws, float* __restrict__ d_out) {
  int b = blockIdx.x, tid = threadIdx.x;
  __shared__ float red[256];
  float e[L / 256];
  float m = -INFINITY;
#pragma unroll
  for (int i = 0; i < L / 256; ++i) {
    e[i] = ws[WS_ENERGY + b * L + i * 256 + tid];
    m = fmaxf(m, e[i]);
  }
  red[tid] = m;
  __syncthreads();
  for (int s = 128; s > 0; s >>= 1) {
    if (tid < s) red[tid] = fmaxf(red[tid], red[tid + s]);
    __syncthreads();
  }
  m = red[0];
  __syncthreads();
  float s0 = 0.f;
#pragma unroll
  for (int i = 0; i < L / 256; ++i) {
    e[i] = expf(e[i] - m);
    s0 += e[i];
  }
  red[tid] = s0;
  __syncthreads();
  for (int s = 128; s > 0; s >>= 1) {
    if (tid < s) red[tid] += red[tid + s];
    __syncthreads();
  }
  float inv = 1.f / red[0];
  float* aw = d_out + (size_t)B * V + (size_t)B * H + (size_t)b * L;
#pragma unroll
  for (int i = 0; i < L / 256; ++i) aw[i * 256 + tid] = e[i] * inv;
}

// ---------------- k4: context partials over l-chunks
__global__ __launch_bounds__(256) void k4_ctx(
    const float* __restrict__ enc, const float* __restrict__ d_out_r,
    float* __restrict__ ws) {
  int b = blockIdx.x, ch = blockIdx.y, tid = threadIdx.x;
  const float* aw = d_out_r + (size_t)B * V + (size_t)B * H + (size_t)b * L;
  float acc = 0.f;
  int l0 = ch * (L / NCH);
  for (int i = 0; i < L / NCH; ++i) {
    int l = l0 + i;
    acc += aw[l] * enc[((size_t)l * B + b) * H + tid];
  }
  ws[WS_PART + (size_t)(ch * B + b) * H + tid] = acc;
}

// ---------------- k5: GRU step; writes h_new to d_out and xcat to ws
__global__ __launch_bounds__(256) void k5_gru(
    const int* __restrict__ input, const float* __restrict__ hidden,
    const float* __restrict__ emb, const float* __restrict__ Wih,
    const float* __restrict__ Whh, const float* __restrict__ bih,
    const float* __restrict__ bhh, float* __restrict__ ws,
    float* __restrict__ d_out) {
  int b = blockIdx.x, tid = threadIdx.x;
  __shared__ float x_s[2 * H];
  __shared__ float h_s[H];
  __shared__ float gi_s[3 * H];
  __shared__ float gh_s[3 * H];
  // reduce context partials
  float c = 0.f;
#pragma unroll
  for (int ch = 0; ch < NCH; ++ch) c += ws[WS_PART + (size_t)(ch * B + b) * H + tid];
  int tok = input[b];
  x_s[tid] = emb[(size_t)tok * H + tid];
  x_s[H + tid] = c;
  h_s[tid] = hidden[b * H + tid];
  __syncthreads();
#pragma unroll
  for (int j0 = 0; j0 < 3; ++j0) {
    int j = j0 * H + tid;
    const float4* wr = (const float4*)(Wih + (size_t)j * 2 * H);
    const float4* xr = (const float4*)x_s;
    float gi = bih[j];
#pragma unroll 4
    for (int k = 0; k < 2 * H / 4; ++k) {
      float4 wv = wr[k], xv = xr[k];
      gi += wv.x * xv.x + wv.y * xv.y + wv.z * xv.z + wv.w * xv.w;
    }
    const float4* wh = (const float4*)(Whh + (size_t)j * H);
    const float4* hr = (const float4*)h_s;
    float gh = bhh[j];
#pragma unroll 4
    for (int k = 0; k < H / 4; ++k) {
      float4 wv = wh[k], hv = hr[k];
      gh += wv.x * hv.x + wv.y * hv.y + wv.z * hv.z + wv.w * hv.w;
    }
    gi_s[j] = gi;
    gh_s[j] = gh;
  }
  __syncthreads();
  float r = 1.f / (1.f + expf(-(gi_s[tid] + gh_s[tid])));
  float z = 1.f / (1.f + expf(-(gi_s[H + tid] + gh_s[H + tid])));
  float n = tanhf(gi_s[2 * H + tid] + r * gh_s[2 * H + tid]);
  float hn = (1.f - z) * n + z * h_s[tid];
  d_out[(size_t)B * V + (size_t)b * H + tid] = hn;
  ws[WS_XCAT + (size_t)b * 2 * H + tid] = hn;
  ws[WS_XCAT + (size_t)b * 2 * H + H + tid] = c;
}

// ---------------- k6: logits = xcat @ out_W^T + out_b  (M=64,N=32000,K=512)
__global__ __launch_bounds__(256) void k6_logits(
    const float* __restrict__ outW, const float* __restrict__ outb,
    const float* __restrict__ ws, float* __restrict__ d_out) {
  __shared__ float As[64 * 65];
  __shared__ float Bs[64 * 65];
  int tid = threadIdx.x;
  int v0 = blockIdx.x * 64;
  int bq = tid & 15, vq = tid >> 4;
  float acc[4][4] = {{0.f}};
  const float* xc = ws + WS_XCAT;
  for (int kc = 0; kc < 8; ++kc) {
    for (int idx = tid; idx < 4096; idx += 256) {
      int r = idx >> 6, k = idx & 63;
      As[r * 65 + k] = xc[r * 512 + kc * 64 + k];
      Bs[r * 65 + k] = outW[(size_t)(v0 + r) * 512 + kc * 64 + k];
    }
    __syncthreads();
#pragma unroll 8
    for (int k = 0; k < 64; ++k) {
      float a0 = As[(bq * 4 + 0) * 65 + k];
      float a1 = As[(bq * 4 + 1) * 65 + k];
      float a2 = As[(bq * 4 + 2) * 65 + k];
      float a3 = As[(bq * 4 + 3) * 65 + k];
      float b0 = Bs[(vq * 4 + 0) * 65 + k];
      float b1 = Bs[(vq * 4 + 1) * 65 + k];
      float b2 = Bs[(vq * 4 + 2) * 65 + k];
      float b3 = Bs[(vq * 4 + 3) * 65 + k];
      acc[0][0] += a0 * b0; acc[0][1] += a0 * b1; acc[0][2] += a0 * b2; acc[0][3] += a0 * b3;
      acc[1][0] += a1 * b0; acc[1][1] += a1 * b1; acc[1][2] += a1 * b2; acc[1][3] += a1 * b3;
      acc[2][0] += a2 * b0; acc[2][1] += a2 * b1; acc[2][2] += a2 * b2; acc[2][3] += a2 * b3;
      acc[3][0] += a3 * b0; acc[3][1] += a3 * b1; acc[3][2] += a3 * b2; acc[3][3] += a3 * b3;
    }
    __syncthreads();
  }
#pragma unroll
  for (int i = 0; i < 4; ++i)
#pragma unroll
    for (int j = 0; j < 4; ++j) {
      int bb = bq * 4 + i;
      int vv = v0 + vq * 4 + j;
      d_out[(size_t)bb * V + vv] = acc[i][j] + outb[vv];
    }
}

// ---------------- k7: per-row max and log-sum-exp over V
__global__ __launch_bounds__(256) void k7_lse(
    const float* __restrict__ d_out_r, float* __restrict__ ws) {
  int b = blockIdx.x, tid = threadIdx.x;
  __shared__ float red[256];
  const float* row = d_out_r + (size_t)b * V;
  float m = -INFINITY;
  for (int i = tid; i < V; i += 256) m = fmaxf(m, row[i]);
  red[tid] = m;
  __syncthreads();
  for (int s = 128; s > 0; s >>= 1) {
    if (tid < s) red[tid] = fmaxf(red[tid], red[tid + s]);
    __syncthreads();
  }
  m = red[0];
  __syncthreads();
  float s0 = 0.f;
  for (int i = tid; i < V; i += 256) s0 += expf(row[i] - m);
  red[tid] = s0;
  __syncthreads();
  for (int s = 128; s > 0; s >>= 1) {
    if (tid < s) red[tid] += red[tid + s];
    __syncthreads();
  }
  if (tid == 0) {
    ws[WS_M + b] = m;
    ws[WS_S + b] = logf(red[0]);
  }
}

// ---------------- k8: out[b,v] -= (m[b] + log s[b])   (in-place log_softmax)
__global__ __launch_bounds__(256) void k8_norm(
    const float* __restrict__ ws, float* __restrict__ d_out) {
  int b = blockIdx.y;
  int v = blockIdx.x * 256 + threadIdx.x;
  float off = ws[WS_M + b] + ws[WS_S + b];
  d_out[(size_t)b * V + v] -= off;
}

extern "C" void kernel_launch(void* const* d_in, const int* in_sizes, int n_in,
                              void* d_out, int out_size, void* d_ws, size_t ws_size,
                              hipStream_t stream) {
  const int* input = (const int*)d_in[0];
  const float* hidden = (const float*)d_in[1];
  const float* enc = (const float*)d_in[2];
  // d_in[3] = use_cuda (ignored)
  const float* emb = (const float*)d_in[4];
  const float* attn_W = (const float*)d_in[5];
  const float* attn_b = (const float*)d_in[6];
  const float* flatten = (const float*)d_in[7];
  const float* gru_Wih = (const float*)d_in[8];
  const float* gru_Whh = (const float*)d_in[9];
  const float* gru_bih = (const float*)d_in[10];
  const float* gru_bhh = (const float*)d_in[11];
  const float* out_W = (const float*)d_in[12];
  const float* out_b = (const float*)d_in[13];
  float* out = (float*)d_out;
  float* ws = (float*)d_ws;

  k1_prep<<<1, 512, 0, stream>>>(attn_W, attn_b, flatten, hidden, ws);
  k2_energy<<<(L * B) / 4, 256, 0, stream>>>(enc, ws);
  k3_softmax<<<B, 256, 0, stream>>>(ws, out);
  k4_ctx<<<dim3(B, NCH), 256, 0, stream>>>(enc, out, ws);
  k5_gru<<<B, 256, 0, stream>>>(input, hidden, emb, gru_Wih, gru_Whh,
                                gru_bih, gru_bhh, ws, out);
  k6_logits<<<V / 64, 256, 0, stream>>>(out_W, out_b, ws, out);
  k7_lse<<<B, 256, 0, stream>>>(out, ws);
  k8_norm<<<dim3(V / 256, B), 256, 0, stream>>>(ws, out);
}

// Round 2
// 397.125 us; speedup vs baseline: 1.2332x; 1.2332x over previous
//
#include <hip/hip_runtime.h>
#include <math.h>

#define H 256
#define V 32000
#define L 2048
#define B 64
#define NCH 16          // context l-chunks

// ws layout (float offsets). Regions are reused once their producer's
// consumer has run:
//   energies (dead after k3)  <- GI/GH  (written by k5a)
//   partials (dead after k4b) <- XCAT2  (written by k5b)
#define WS_W      0                       // [2H] = attn_W^T @ flatten
#define WS_BIAS   512                     // [1]
#define WS_EH     513                     // [B]
#define WS_ENERGY 640                     // [B*L]
#define WS_GI     640                     // [B*3H]  (overlaps energies)
#define WS_GH     (640 + B*3*H)           // [B*3H]  (overlaps energies)
#define WS_PART   (640 + B*L)             // [NCH*B*H] context partials
#define WS_XCAT2  WS_PART                 // [B*2H] = [h_new ; context] (overlaps partials)
#define WS_X      (WS_PART + NCH*B*H)     // [B*2H] = [emb ; context]  (GRU input)
#define WS_M      (WS_X + B*2*H)          // [B] row max
#define WS_S      (WS_M + B)              // [B] log(sum exp)

// ---------------- k1: w = attn_W^T @ fvec, bias = fvec.attn_b, e_h = h @ w[:H]
__global__ __launch_bounds__(512) void k1_prep(
    const float* __restrict__ attn_W, const float* __restrict__ attn_b,
    const float* __restrict__ flatten, const float* __restrict__ hidden,
    float* __restrict__ ws) {
  __shared__ float fv[H];
  __shared__ float w_s[2 * H];
  __shared__ float red[H];
  int tid = threadIdx.x;  // 512 threads
  if (tid < H) fv[tid] = flatten[tid];
  __syncthreads();
  float acc = 0.f;
  for (int hh = 0; hh < H; ++hh) acc += attn_W[hh * 2 * H + tid] * fv[hh];
  w_s[tid] = acc;
  ws[WS_W + tid] = acc;
  if (tid < H) red[tid] = fv[tid] * attn_b[tid];
  __syncthreads();
  for (int s = H / 2; s > 0; s >>= 1) {
    if (tid < s) red[tid] += red[tid + s];
    __syncthreads();
  }
  if (tid == 0) ws[WS_BIAS] = red[0];
  if (tid < B) {
    float a = 0.f;
    for (int h = 0; h < H; ++h) a += hidden[tid * H + h] * w_s[h];
    ws[WS_EH + tid] = a;
  }
}

// ---------------- k2: energies[b,l] = enc[l,b,:].w[H:] + e_h[b] + bias
__global__ __launch_bounds__(256) void k2_energy(
    const float* __restrict__ enc, float* __restrict__ ws) {
  int tid = threadIdx.x;
  int lane = tid & 63;
  size_t pair = (size_t)blockIdx.x * 4 + (tid >> 6);  // < L*B = 131072
  const float4* e4 = (const float4*)enc;
  float4 e = e4[pair * (H / 4) + lane];
  float4 w2 = ((const float4*)(ws + WS_W + H))[lane];
  float v = e.x * w2.x + e.y * w2.y + e.z * w2.z + e.w * w2.w;
  for (int off = 32; off > 0; off >>= 1) v += __shfl_xor(v, off, 64);
  if (lane == 0) {
    int b = (int)(pair & (B - 1));
    int l = (int)(pair >> 6);
    ws[WS_ENERGY + b * L + l] = v + ws[WS_EH + b] + ws[WS_BIAS];
  }
}

// ---------------- k3: softmax over L per batch row -> attn_weights in d_out
__global__ __launch_bounds__(256) void k3_softmax(
    const float* __restrict__ ws, float* __restrict__ d_out) {
  int b = blockIdx.x, tid = threadIdx.x;
  __shared__ float red[256];
  float e[L / 256];
  float m = -INFINITY;
#pragma unroll
  for (int i = 0; i < L / 256; ++i) {
    e[i] = ws[WS_ENERGY + b * L + i * 256 + tid];
    m = fmaxf(m, e[i]);
  }
  red[tid] = m;
  __syncthreads();
  for (int s = 128; s > 0; s >>= 1) {
    if (tid < s) red[tid] = fmaxf(red[tid], red[tid + s]);
    __syncthreads();
  }
  m = red[0];
  __syncthreads();
  float s0 = 0.f;
#pragma unroll
  for (int i = 0; i < L / 256; ++i) {
    e[i] = expf(e[i] - m);
    s0 += e[i];
  }
  red[tid] = s0;
  __syncthreads();
  for (int s = 128; s > 0; s >>= 1) {
    if (tid < s) red[tid] += red[tid + s];
    __syncthreads();
  }
  float inv = 1.f / red[0];
  float* aw = d_out + (size_t)B * V + (size_t)B * H + (size_t)b * L;
#pragma unroll
  for (int i = 0; i < L / 256; ++i) aw[i * 256 + tid] = e[i] * inv;
}

// ---------------- k4: context partials over l-chunks
__global__ __launch_bounds__(256) void k4_ctx(
    const float* __restrict__ enc, const float* __restrict__ d_out_r,
    float* __restrict__ ws) {
  int b = blockIdx.x, ch = blockIdx.y, tid = threadIdx.x;
  const float* aw = d_out_r + (size_t)B * V + (size_t)B * H + (size_t)b * L;
  float acc = 0.f;
  int l0 = ch * (L / NCH);
  for (int i = 0; i < L / NCH; ++i) {
    int l = l0 + i;
    acc += aw[l] * enc[((size_t)l * B + b) * H + tid];
  }
  ws[WS_PART + (size_t)(ch * B + b) * H + tid] = acc;
}

// ---------------- k4b: reduce partials -> context; assemble x = [emb; c]
__global__ __launch_bounds__(256) void k4b_xcat(
    const int* __restrict__ input, const float* __restrict__ emb,
    float* __restrict__ ws) {
  int b = blockIdx.x, tid = threadIdx.x;
  float c = 0.f;
#pragma unroll
  for (int ch = 0; ch < NCH; ++ch)
    c += ws[WS_PART + (size_t)(ch * B + b) * H + tid];
  int tok = input[b];
  ws[WS_X + (size_t)b * 2 * H + tid] = emb[(size_t)tok * H + tid];
  ws[WS_X + (size_t)b * 2 * H + H + tid] = c;
}

// ---------------- k5a: gi[b,j] = Wih[j,:].x[b,:] + bih[j]
//                       gh[b,j] = Whh[j,:].h[b,:] + bhh[j]
// one wave per (j,b) pair: 768*64 = 49152 waves.
__global__ __launch_bounds__(256) void k5a_gates_mv(
    const float* __restrict__ Wih, const float* __restrict__ Whh,
    const float* __restrict__ bih, const float* __restrict__ bhh,
    const float* __restrict__ hidden, float* __restrict__ ws) {
  int tid = threadIdx.x, lane = tid & 63;
  int p = blockIdx.x * 4 + (tid >> 6);   // p = j*64 + b
  int j = p >> 6, b = p & 63;
  const float4* wr = (const float4*)(Wih + (size_t)j * 2 * H);   // 128 float4
  const float4* xr = (const float4*)(ws + WS_X + (size_t)b * 2 * H);
  float4 wa = wr[lane],      xa = xr[lane];
  float4 wb = wr[64 + lane], xb = xr[64 + lane];
  float gi = wa.x * xa.x + wa.y * xa.y + wa.z * xa.z + wa.w * xa.w
           + wb.x * xb.x + wb.y * xb.y + wb.z * xb.z + wb.w * xb.w;
  const float4* wh = (const float4*)(Whh + (size_t)j * H);       // 64 float4
  const float4* hr = (const float4*)(hidden + (size_t)b * H);
  float4 wc = wh[lane], hc = hr[lane];
  float gh = wc.x * hc.x + wc.y * hc.y + wc.z * hc.z + wc.w * hc.w;
  for (int off = 32; off > 0; off >>= 1) {
    gi += __shfl_xor(gi, off, 64);
    gh += __shfl_xor(gh, off, 64);
  }
  if (lane == 0) {
    ws[WS_GI + (size_t)b * 3 * H + j] = gi + bih[j];
    ws[WS_GH + (size_t)b * 3 * H + j] = gh + bhh[j];
  }
}

// ---------------- k5b: gates elementwise; h_new -> d_out; xcat2 = [h_new; c]
__global__ __launch_bounds__(256) void k5b_gates(
    const float* __restrict__ hidden, float* __restrict__ ws,
    float* __restrict__ d_out) {
  int b = blockIdx.x, tid = threadIdx.x;
  float gir = ws[WS_GI + (size_t)b * 3 * H + tid];
  float giz = ws[WS_GI + (size_t)b * 3 * H + H + tid];
  float gin = ws[WS_GI + (size_t)b * 3 * H + 2 * H + tid];
  float ghr = ws[WS_GH + (size_t)b * 3 * H + tid];
  float ghz = ws[WS_GH + (size_t)b * 3 * H + H + tid];
  float ghn = ws[WS_GH + (size_t)b * 3 * H + 2 * H + tid];
  float c = ws[WS_X + (size_t)b * 2 * H + H + tid];
  float h = hidden[(size_t)b * H + tid];
  float r = 1.f / (1.f + expf(-(gir + ghr)));
  float z = 1.f / (1.f + expf(-(giz + ghz)));
  float n = tanhf(gin + r * ghn);
  float hn = (1.f - z) * n + z * h;
  d_out[(size_t)B * V + (size_t)b * H + tid] = hn;
  ws[WS_XCAT2 + (size_t)b * 2 * H + tid] = hn;
  ws[WS_XCAT2 + (size_t)b * 2 * H + H + tid] = c;
}

// ---------------- k6: logits = xcat2 @ out_W^T + out_b  (M=64,N=32000,K=512)
__global__ __launch_bounds__(256) void k6_logits(
    const float* __restrict__ outW, const float* __restrict__ outb,
    const float* __restrict__ ws, float* __restrict__ d_out) {
  __shared__ float As[64 * 65];
  __shared__ float Bs[64 * 65];
  int tid = threadIdx.x;
  int v0 = blockIdx.x * 64;
  int bq = tid & 15, vq = tid >> 4;
  float acc[4][4] = {{0.f}};
  const float* xc = ws + WS_XCAT2;
  for (int kc = 0; kc < 8; ++kc) {
    for (int idx = tid; idx < 4096; idx += 256) {
      int r = idx >> 6, k = idx & 63;
      As[r * 65 + k] = xc[r * 512 + kc * 64 + k];
      Bs[r * 65 + k] = outW[(size_t)(v0 + r) * 512 + kc * 64 + k];
    }
    __syncthreads();
#pragma unroll 8
    for (int k = 0; k < 64; ++k) {
      float a0 = As[(bq * 4 + 0) * 65 + k];
      float a1 = As[(bq * 4 + 1) * 65 + k];
      float a2 = As[(bq * 4 + 2) * 65 + k];
      float a3 = As[(bq * 4 + 3) * 65 + k];
      float b0 = Bs[(vq * 4 + 0) * 65 + k];
      float b1 = Bs[(vq * 4 + 1) * 65 + k];
      float b2 = Bs[(vq * 4 + 2) * 65 + k];
      float b3 = Bs[(vq * 4 + 3) * 65 + k];
      acc[0][0] += a0 * b0; acc[0][1] += a0 * b1; acc[0][2] += a0 * b2; acc[0][3] += a0 * b3;
      acc[1][0] += a1 * b0; acc[1][1] += a1 * b1; acc[1][2] += a1 * b2; acc[1][3] += a1 * b3;
      acc[2][0] += a2 * b0; acc[2][1] += a2 * b1; acc[2][2] += a2 * b2; acc[2][3] += a2 * b3;
      acc[3][0] += a3 * b0; acc[3][1] += a3 * b1; acc[3][2] += a3 * b2; acc[3][3] += a3 * b3;
    }
    __syncthreads();
  }
#pragma unroll
  for (int i = 0; i < 4; ++i)
#pragma unroll
    for (int j = 0; j < 4; ++j) {
      int bb = bq * 4 + i;
      int vv = v0 + vq * 4 + j;
      d_out[(size_t)bb * V + vv] = acc[i][j] + outb[vv];
    }
}

// ---------------- k7: per-row max and log-sum-exp over V
__global__ __launch_bounds__(1024) void k7_lse(
    const float* __restrict__ d_out_r, float* __restrict__ ws) {
  int b = blockIdx.x, tid = threadIdx.x;
  __shared__ float red[1024];
  const float* row = d_out_r + (size_t)b * V;
  float m = -INFINITY;
  for (int i = tid; i < V; i += 1024) m = fmaxf(m, row[i]);
  red[tid] = m;
  __syncthreads();
  for (int s = 512; s > 0; s >>= 1) {
    if (tid < s) red[tid] = fmaxf(red[tid], red[tid + s]);
    __syncthreads();
  }
  m = red[0];
  __syncthreads();
  float s0 = 0.f;
  for (int i = tid; i < V; i += 1024) s0 += expf(row[i] - m);
  red[tid] = s0;
  __syncthreads();
  for (int s = 512; s > 0; s >>= 1) {
    if (tid < s) red[tid] += red[tid + s];
    __syncthreads();
  }
  if (tid == 0) {
    ws[WS_M + b] = m;
    ws[WS_S + b] = logf(red[0]);
  }
}

// ---------------- k8: out[b,v] -= (m[b] + log s[b])
__global__ __launch_bounds__(256) void k8_norm(
    const float* __restrict__ ws, float* __restrict__ d_out) {
  int b = blockIdx.y;
  int v = blockIdx.x * 256 + threadIdx.x;
  float off = ws[WS_M + b] + ws[WS_S + b];
  d_out[(size_t)b * V + v] -= off;
}

extern "C" void kernel_launch(void* const* d_in, const int* in_sizes, int n_in,
                              void* d_out, int out_size, void* d_ws, size_t ws_size,
                              hipStream_t stream) {
  const int* input = (const int*)d_in[0];
  const float* hidden = (const float*)d_in[1];
  const float* enc = (const float*)d_in[2];
  const float* emb = (const float*)d_in[4];
  const float* attn_W = (const float*)d_in[5];
  const float* attn_b = (const float*)d_in[6];
  const float* flatten = (const float*)d_in[7];
  const float* gru_Wih = (const float*)d_in[8];
  const float* gru_Whh = (const float*)d_in[9];
  const float* gru_bih = (const float*)d_in[10];
  const float* gru_bhh = (const float*)d_in[11];
  const float* out_W = (const float*)d_in[12];
  const float* out_b = (const float*)d_in[13];
  float* out = (float*)d_out;
  float* ws = (float*)d_ws;

  k1_prep<<<1, 512, 0, stream>>>(attn_W, attn_b, flatten, hidden, ws);
  k2_energy<<<(L * B) / 4, 256, 0, stream>>>(enc, ws);
  k3_softmax<<<B, 256, 0, stream>>>(ws, out);
  k4_ctx<<<dim3(B, NCH), 256, 0, stream>>>(enc, out, ws);
  k4b_xcat<<<B, 256, 0, stream>>>(input, emb, ws);
  k5a_gates_mv<<<(3 * H * B) / 4, 256, 0, stream>>>(gru_Wih, gru_Whh, gru_bih,
                                                    gru_bhh, hidden, ws);
  k5b_gates<<<B, 256, 0, stream>>>(hidden, ws, out);
  k6_logits<<<V / 64, 256, 0, stream>>>(out_W, out_b, ws, out);
  k7_lse<<<B, 1024, 0, stream>>>(out, ws);
  k8_norm<<<dim3(V / 256, B), 256, 0, stream>>>(ws, out);
}